// Round 2
// baseline (433.843 us; speedup 1.0000x reference)
//
#include <hip/hip_runtime.h>
#include <hip/hip_bf16.h>

#define NN 10000
#define NE 320000

typedef __bf16 bf16x8 __attribute__((ext_vector_type(8)));
typedef float  f32x4  __attribute__((ext_vector_type(4)));

__device__ __forceinline__ float bf2f(ushort u){
  union { uint i; float f; } c; c.i = ((uint)u) << 16; return c.f;
}
__device__ __forceinline__ ushort f2bf(float f){
  union { float f; uint i; } c; c.f = f;
  uint x = c.i;
  return (ushort)((x + 0x7FFFu + ((x >> 16) & 1u)) >> 16);
}
__device__ __forceinline__ float gelu_erf(float x){
  return 0.5f * x * (1.0f + erff(x * 0.70710678118654752f));
}
#define MFMA16(a,b,c) __builtin_amdgcn_mfma_f32_16x16x32_bf16((a),(b),(c),0,0,0)

// ---------------- dtype detection: flag=1 -> inputs are fp32 ----------------
// bf16-pair words: low 16 bits are a bf16 sample -> "exponent" bits14-7 in [100,140]
// fp32 words: bits 14-7 are low mantissa bits -> ~uniform -> ~16% in range
__global__ void k_detect(const uint* __restrict__ w, int* __restrict__ flag){
  int t = threadIdx.x;
  uint cnt = 0;
  for (int i = t; i < 4096; i += 256){
    uint v = w[i * 63];              // stride through first ~256K words (safe in both dtypes)
    uint e = (v >> 7) & 0xFF;
    if (e >= 100 && e <= 140) cnt++;
  }
  __shared__ uint red[256];
  red[t] = cnt; __syncthreads();
  for (int s = 128; s > 0; s >>= 1){
    if (t < s) red[t] += red[t + s];
    __syncthreads();
  }
  if (t == 0) *flag = (red[0] < 2048) ? 1 : 0;
}

// ---------------- canonicalize big tensors to bf16 (vectorized x4) ----------------
__global__ void k_cvt4(const void* __restrict__ in, ushort* __restrict__ out,
                       int n4, const int* __restrict__ flag){
  int i = blockIdx.x * 256 + threadIdx.x;
  if (i >= n4) return;
  if (*flag){
    float4 v = ((const float4*)in)[i];
    ushort4 o;
    o.x = f2bf(v.x); o.y = f2bf(v.y); o.z = f2bf(v.z); o.w = f2bf(v.w);
    ((ushort4*)out)[i] = o;
  } else {
    ((ushort4*)out)[i] = ((const ushort4*)in)[i];
  }
}

// small params: SB = [b1|b2|q_b|kv_b|o_b1|o_b2|ln_g|ln_b] (8x128), KVW2 = kv_w[128:192][:]
__global__ void k_cvt_params(const void* b1, const void* b2, const void* qb, const void* kvb,
                             const void* ob1, const void* ob2, const void* lg, const void* lb,
                             const void* kvw, ushort* __restrict__ SB, ushort* __restrict__ KVW2,
                             const int* __restrict__ flag){
  int i = blockIdx.x * 256 + threadIdx.x;
  int f = *flag;
  if (i < 1024){
    const void* ps[8] = {b1, b2, qb, kvb, ob1, ob2, lg, lb};
    const void* p = ps[i >> 7];
    int j = i & 127;
    SB[i] = f ? f2bf(((const float*)p)[j]) : ((const ushort*)p)[j];
  } else if (i < 1024 + 64 * 128){
    int j = i - 1024;
    KVW2[j] = f ? f2bf(((const float*)kvw)[16384 + j]) : ((const ushort*)kvw)[16384 + j];
  }
}

// transpose weight [K][128] -> bf16 [128][K], flag-aware read
__global__ void k_tr(const void* __restrict__ in, ushort* __restrict__ out, int K,
                     const int* __restrict__ flag){
  int idx = blockIdx.x * 256 + threadIdx.x;
  if (idx < 128 * K){
    int j = idx / K, k = idx - j * K;
    out[idx] = *flag ? f2bf(((const float*)in)[k * 128 + j])
                     : ((const ushort*)in)[k * 128 + j];
  }
}

__global__ void k_last(const int* __restrict__ dst, int* __restrict__ last){
  int e = blockIdx.x * 256 + threadIdx.x;
  if (e < NE) atomicMax(&last[dst[e]], e);
}

// ---------------- edge kernel: fused m_in@W1 -> gelu -> @W2 -> atomic scatter ----------------
__global__ __launch_bounds__(256) void k_edge(
    const ushort* __restrict__ NF, const ushort* __restrict__ EA,
    const int* __restrict__ srcI, const int* __restrict__ dstI,
    const ushort* __restrict__ W1T, const ushort* __restrict__ W2T,
    const ushort* __restrict__ b1,  const ushort* __restrict__ b2,
    float* __restrict__ agg)
{
  __shared__ int sIdx[128], dIdx[128];
  __shared__ __align__(16) char Hs[128 * 256];   // H[128][128] bf16, XOR-swizzled
  int t = threadIdx.x;
  int e0 = blockIdx.x * 128;
  if (t < 128){ sIdx[t] = srcI[e0 + t]; dIdx[t] = dstI[e0 + t]; }
  __syncthreads();

  int l = t & 63, w = t >> 6;
  int rw = w >> 1, cw = w & 1;
  int m = l & 15, g = l >> 4;
  const f32x4 FZ = {0.f, 0.f, 0.f, 0.f};

  f32x4 acc[4][4];
  #pragma unroll
  for (int i = 0; i < 4; ++i)
    #pragma unroll
    for (int j = 0; j < 4; ++j) acc[i][j] = FZ;

  int koff = g * 8;
  // GEMM1: K = 320 = [src 128 | dst 128 | ea 64]
  #pragma unroll
  for (int ks = 0; ks < 10; ++ks){
    bf16x8 af[4], bfr[4];
    #pragma unroll
    for (int rt = 0; rt < 4; ++rt){
      int rl = rw * 64 + rt * 16 + m;
      const ushort* p;
      if (ks < 4)      p = NF + (size_t)sIdx[rl] * 128 + ks * 32 + koff;
      else if (ks < 8) p = NF + (size_t)dIdx[rl] * 128 + (ks - 4) * 32 + koff;
      else             p = EA + (size_t)(e0 + rl) * 64 + (ks - 8) * 32 + koff;
      af[rt] = *reinterpret_cast<const bf16x8*>(p);
    }
    #pragma unroll
    for (int ct = 0; ct < 4; ++ct){
      int col = cw * 64 + ct * 16 + m;
      bfr[ct] = *reinterpret_cast<const bf16x8*>(W1T + (size_t)col * 320 + ks * 32 + koff);
    }
    #pragma unroll
    for (int rt = 0; rt < 4; ++rt)
      #pragma unroll
      for (int ct = 0; ct < 4; ++ct)
        acc[rt][ct] = MFMA16(af[rt], bfr[ct], acc[rt][ct]);
  }

  // bias + gelu -> H to LDS (swizzled)
  #pragma unroll
  for (int ct = 0; ct < 4; ++ct){
    int col = cw * 64 + ct * 16 + m;
    float bb = bf2f(b1[col]);
    #pragma unroll
    for (int rt = 0; rt < 4; ++rt){
      #pragma unroll
      for (int r = 0; r < 4; ++r){
        int row = rw * 64 + rt * 16 + g * 4 + r;
        float h = gelu_erf(acc[rt][ct][r] + bb);
        int byte = (row * 256 + col * 2) ^ ((row & 7) << 4);
        *reinterpret_cast<ushort*>(&Hs[byte]) = f2bf(h);
      }
    }
  }
  __syncthreads();

  // GEMM2: K = 128
  f32x4 acc2[4][4];
  #pragma unroll
  for (int i = 0; i < 4; ++i)
    #pragma unroll
    for (int j = 0; j < 4; ++j) acc2[i][j] = FZ;

  #pragma unroll
  for (int ks = 0; ks < 4; ++ks){
    bf16x8 af[4], bfr[4];
    #pragma unroll
    for (int rt = 0; rt < 4; ++rt){
      int row = rw * 64 + rt * 16 + m;
      int byte = (row * 256 + (ks * 32 + koff) * 2) ^ ((row & 7) << 4);
      af[rt] = *reinterpret_cast<const bf16x8*>(&Hs[byte]);
    }
    #pragma unroll
    for (int ct = 0; ct < 4; ++ct){
      int col = cw * 64 + ct * 16 + m;
      bfr[ct] = *reinterpret_cast<const bf16x8*>(W2T + (size_t)col * 128 + ks * 32 + koff);
    }
    #pragma unroll
    for (int rt = 0; rt < 4; ++rt)
      #pragma unroll
      for (int ct = 0; ct < 4; ++ct)
        acc2[rt][ct] = MFMA16(af[rt], bfr[ct], acc2[rt][ct]);
  }

  // epilogue: + b2, atomic scatter-add into agg[dst]
  #pragma unroll
  for (int ct = 0; ct < 4; ++ct){
    int col = cw * 64 + ct * 16 + m;
    float bb = bf2f(b2[col]);
    #pragma unroll
    for (int rt = 0; rt < 4; ++rt){
      #pragma unroll
      for (int r = 0; r < 4; ++r){
        int rl = rw * 64 + rt * 16 + g * 4 + r;
        int d = dIdx[rl];
        unsafeAtomicAdd(&agg[(size_t)d * 128 + col], acc2[rt][ct][r] + bb);
      }
    }
  }
}

// ---------------- generic node GEMM: A[M][K]bf16 @ WT[128][K] ----------------
// MODE 0: +bias -> bf16 ; MODE 1: +bias, gelu -> bf16 ; MODE 2: +bias -> f32
template<int K, int MODE>
__global__ __launch_bounds__(256) void k_gemm(
    const ushort* __restrict__ A, const ushort* __restrict__ WT,
    const ushort* __restrict__ bias, void* __restrict__ out, int M)
{
  int t = threadIdx.x;
  int l = t & 63, w = t >> 6;
  int m = l & 15, g = l >> 4;
  int row0 = blockIdx.x * 64 + w * 16;
  const f32x4 FZ = {0.f, 0.f, 0.f, 0.f};
  f32x4 acc[8];
  #pragma unroll
  for (int i = 0; i < 8; ++i) acc[i] = FZ;

  int arow = row0 + m; if (arow >= M) arow = M - 1;
  #pragma unroll
  for (int ks = 0; ks < K / 32; ++ks){
    int koff = ks * 32 + g * 8;
    bf16x8 a = *reinterpret_cast<const bf16x8*>(A + (size_t)arow * K + koff);
    #pragma unroll
    for (int nt = 0; nt < 8; ++nt){
      bf16x8 b = *reinterpret_cast<const bf16x8*>(WT + (size_t)(nt * 16 + m) * K + koff);
      acc[nt] = MFMA16(a, b, acc[nt]);
    }
  }
  #pragma unroll
  for (int nt = 0; nt < 8; ++nt){
    int col = nt * 16 + m;
    float bb = bf2f(bias[col]);
    #pragma unroll
    for (int r = 0; r < 4; ++r){
      int row = row0 + g * 4 + r;
      if (row < M){
        float v = acc[nt][r] + bb;
        if (MODE == 1) v = gelu_erf(v);
        if (MODE == 2) ((float*)out)[(size_t)row * 128 + col] = v;
        else           ((ushort*)out)[(size_t)row * 128 + col] = f2bf(v);
      }
    }
  }
}

// ---------------- attention logits at last-edges ----------------
__global__ __launch_bounds__(256) void k_attn(
    const ushort* __restrict__ Qb, const ushort* __restrict__ KV1,
    const ushort* __restrict__ EA, const ushort* __restrict__ KVW2,
    const int* __restrict__ srcI, const int* __restrict__ last,
    float* __restrict__ attn)
{
  __shared__ float ea_s[16][64];
  __shared__ int eN[16], sN[16];
  int t = threadIdx.x;
  int n0 = blockIdx.x * 16;
  if (t < 16){
    int e = last[n0 + t];
    eN[t] = e;
    sN[t] = (e >= 0) ? srcI[e] : 0;
  }
  __syncthreads();
  for (int i = t; i < 1024; i += 256){
    int nn = i >> 6, k = i & 63;
    int e = eN[nn];
    int ee = (e >= 0) ? e : 0;                       // no speculative OOB
    float v = bf2f(EA[(size_t)ee * 64 + k]);
    ea_s[nn][k] = (e >= 0) ? v : 0.0f;
  }
  __syncthreads();

  int j = t & 127;
  int half = t >> 7;
  float acc[8];
  #pragma unroll
  for (int i = 0; i < 8; ++i) acc[i] = 0.f;
  for (int k = 0; k < 64; ++k){
    float wv = bf2f(KVW2[(size_t)k * 128 + j]);
    #pragma unroll
    for (int nn = 0; nn < 8; ++nn) acc[nn] += ea_s[half * 8 + nn][k] * wv;
  }
  #pragma unroll
  for (int nn = 0; nn < 8; ++nn){
    int nl = half * 8 + nn;
    int n = n0 + nl;
    int e = eN[nl];
    float kvv = acc[nn] + bf2f(KV1[(size_t)sN[nl] * 128 + j]);
    float qv  = bf2f(Qb[(size_t)n * 128 + j]);
    float p = qv * kvv;
    p += __shfl_xor(p, 1); p += __shfl_xor(p, 2);
    p += __shfl_xor(p, 4); p += __shfl_xor(p, 8);
    if ((j & 15) == 0 && e >= 0) attn[(size_t)n * 8 + (j >> 4)] = p * 0.25f;
  }
}

// ---------------- softmax over node axis (per head), single block ----------------
__global__ __launch_bounds__(1024) void k_softmax(
    const float* __restrict__ attn, const int* __restrict__ last,
    float* __restrict__ attnw)
{
  __shared__ float red[128][8];
  __shared__ float Ms[8], Ss[8];
  int t = threadIdx.x;
  int h = t & 7, c = t >> 3;
  float mx = -3.0e38f;
  for (int n = c; n < NN; n += 128)
    if (last[n] >= 0) mx = fmaxf(mx, attn[(size_t)n * 8 + h]);
  red[c][h] = mx; __syncthreads();
  for (int s = 64; s > 0; s >>= 1){
    if (c < s) red[c][h] = fmaxf(red[c][h], red[c + s][h]);
    __syncthreads();
  }
  if (t < 8) Ms[t] = red[0][t];
  __syncthreads();
  float M = Ms[h];
  float sm = 0.f;
  for (int n = c; n < NN; n += 128)
    if (last[n] >= 0) sm += expf(attn[(size_t)n * 8 + h] - M);
  red[c][h] = sm; __syncthreads();
  for (int s = 64; s > 0; s >>= 1){
    if (c < s) red[c][h] += red[c + s][h];
    __syncthreads();
  }
  if (t < 8) Ss[t] = red[0][t];
  __syncthreads();
  for (int i = t; i < NN * 8; i += 1024){
    int n = i >> 3, hh = i & 7;
    float val = 0.0f;
    if (last[n] >= 0) val = expf(attn[i] - Ms[hh]) / Ss[hh];
    attnw[i] = val;
  }
}

// ---------------- build h_in = [NF | agg * attnw] ----------------
__global__ void k_hin(const ushort* __restrict__ NF, const float* __restrict__ agg,
                      const float* __restrict__ attnw, ushort* __restrict__ h_in)
{
  int i = blockIdx.x * 256 + threadIdx.x;
  if (i < NN * 256){
    int n = i >> 8, c = i & 255;
    if (c < 128) h_in[i] = NF[(size_t)n * 128 + c];
    else {
      int cc = c - 128;
      h_in[i] = f2bf(agg[(size_t)n * 128 + cc] * attnw[(size_t)n * 8 + (cc >> 4)]);
    }
  }
}

// ---------------- residual + LayerNorm, flag-aware output dtype ----------------
__global__ __launch_bounds__(64) void k_ln(
    const ushort* __restrict__ NF, const float* __restrict__ T2,
    const ushort* __restrict__ g, const ushort* __restrict__ b,
    void* __restrict__ out, const int* __restrict__ flag)
{
  int n = blockIdx.x, l = threadIdx.x;
  float x0 = bf2f(NF[(size_t)n * 128 + 2 * l])     + T2[(size_t)n * 128 + 2 * l];
  float x1 = bf2f(NF[(size_t)n * 128 + 2 * l + 1]) + T2[(size_t)n * 128 + 2 * l + 1];
  float s = x0 + x1, q = x0 * x0 + x1 * x1;
  #pragma unroll
  for (int msk = 1; msk < 64; msk <<= 1){
    s += __shfl_xor(s, msk);
    q += __shfl_xor(q, msk);
  }
  float mean = s * (1.0f / 128.0f);
  float var  = q * (1.0f / 128.0f) - mean * mean;
  float rs = rsqrtf(var + 1e-5f);
  float y0 = (x0 - mean) * rs * bf2f(g[2 * l])     + bf2f(b[2 * l]);
  float y1 = (x1 - mean) * rs * bf2f(g[2 * l + 1]) + bf2f(b[2 * l + 1]);
  if (*flag){
    ((float*)out)[(size_t)n * 128 + 2 * l]     = y0;
    ((float*)out)[(size_t)n * 128 + 2 * l + 1] = y1;
  } else {
    uint pack = (uint)f2bf(y0) | ((uint)f2bf(y1) << 16);
    *reinterpret_cast<uint*>(&((ushort*)out)[(size_t)n * 128 + 2 * l]) = pack;
  }
}

// ---------------- host ----------------
extern "C" void kernel_launch(void* const* d_in, const int* in_sizes, int n_in,
                              void* d_out, int out_size, void* d_ws, size_t ws_size,
                              hipStream_t stream)
{
  const void* NF0     = d_in[0];
  const void* EA0     = d_in[1];
  const void* msg_w1  = d_in[2];
  const void* msg_b1  = d_in[3];
  const void* msg_w2  = d_in[4];
  const void* msg_b2  = d_in[5];
  const void* q_w     = d_in[6];
  const void* q_b     = d_in[7];
  const void* kv_w    = d_in[8];
  const void* kv_b    = d_in[9];
  const void* o_w1    = d_in[10];
  const void* o_b1    = d_in[11];
  const void* o_w2    = d_in[12];
  const void* o_b2    = d_in[13];
  const void* ln_g    = d_in[14];
  const void* ln_b    = d_in[15];
  const int*  srcI    = (const int*)d_in[16];
  const int*  dstI    = srcI + NE;

  char* ws = (char*)d_ws;
  size_t off = 0;
  auto alloc = [&](size_t bytes) -> void* {
    void* p = ws + off;
    off = (off + bytes + 255) & ~(size_t)255;
    return p;
  };
  int*    flag = (int*)   alloc(4);
  ushort* NFc  = (ushort*)alloc((size_t)NN * 128 * 2);
  ushort* EAc  = (ushort*)alloc((size_t)NE * 64 * 2);
  ushort* SB   = (ushort*)alloc(8 * 128 * 2);
  ushort* KVW2 = (ushort*)alloc(64 * 128 * 2);
  ushort* W1T  = (ushort*)alloc(128 * 320 * 2);
  ushort* W2T  = (ushort*)alloc(128 * 128 * 2);
  ushort* QT   = (ushort*)alloc(128 * 128 * 2);
  ushort* KVT  = (ushort*)alloc(128 * 128 * 2);
  ushort* O1T  = (ushort*)alloc(128 * 256 * 2);
  ushort* O2T  = (ushort*)alloc(128 * 128 * 2);
  int*    last = (int*)   alloc(NN * 4);
  float*  attn = (float*) alloc(NN * 8 * 4);
  float*  attnw= (float*) alloc(NN * 8 * 4);
  ushort* Qb   = (ushort*)alloc((size_t)NN * 128 * 2);
  ushort* KV1  = (ushort*)alloc((size_t)NN * 128 * 2);
  float*  agg  = (float*) alloc((size_t)NN * 128 * 4);
  ushort* h_in = (ushort*)alloc((size_t)NN * 256 * 2);
  ushort* T1   = (ushort*)alloc((size_t)NN * 128 * 2);
  float*  T2   = (float*)Qb;   // overlap: Qb+KV1 dead once T2 is written

  k_detect<<<1, 256, 0, stream>>>((const uint*)NF0, flag);

  hipMemsetAsync(last, 0xFF, NN * 4, stream);
  hipMemsetAsync(agg, 0, (size_t)NN * 128 * 4, stream);

  // canonicalize inputs to bf16
  k_cvt4<<<(NN * 128 / 4 + 255) / 256, 256, 0, stream>>>(NF0, NFc, NN * 128 / 4, flag);
  k_cvt4<<<(NE * 64 / 4 + 255) / 256, 256, 0, stream>>>(EA0, EAc, NE * 64 / 4, flag);
  k_cvt_params<<<37, 256, 0, stream>>>(msg_b1, msg_b2, q_b, kv_b, o_b1, o_b2, ln_g, ln_b,
                                       kv_w, SB, KVW2, flag);

  // weight transposes (flag-aware read)
  k_tr<<<(128 * 320 + 255) / 256, 256, 0, stream>>>(msg_w1, W1T, 320, flag);
  k_tr<<<(128 * 128 + 255) / 256, 256, 0, stream>>>(msg_w2, W2T, 128, flag);
  k_tr<<<(128 * 128 + 255) / 256, 256, 0, stream>>>(q_w,    QT,  128, flag);
  k_tr<<<(128 * 128 + 255) / 256, 256, 0, stream>>>(kv_w,   KVT, 128, flag);
  k_tr<<<(128 * 256 + 255) / 256, 256, 0, stream>>>(o_w1,   O1T, 256, flag);
  k_tr<<<(128 * 128 + 255) / 256, 256, 0, stream>>>(o_w2,   O2T, 128, flag);

  k_last<<<(NE + 255) / 256, 256, 0, stream>>>(dstI, last);

  // node pre-GEMMs: Qb = NF@q_w + q_b ; KV1 = NF@kv_w[:128] + kv_b
  k_gemm<128, 0><<<157, 256, 0, stream>>>(NFc, QT,  SB + 256, Qb,  NN);
  k_gemm<128, 0><<<157, 256, 0, stream>>>(NFc, KVT, SB + 384, KV1, NN);

  // edge MLP + scatter
  k_edge<<<NE / 128, 256, 0, stream>>>(NFc, EAc, srcI, dstI, W1T, W2T, SB + 0, SB + 128, agg);

  // attention
  k_attn<<<NN / 16, 256, 0, stream>>>(Qb, KV1, EAc, KVW2, srcI, last, attn);
  k_softmax<<<1, 1024, 0, stream>>>(attn, last, attnw);

  // output MLP
  k_hin<<<(NN * 256 + 255) / 256, 256, 0, stream>>>(NFc, agg, attnw, h_in);
  k_gemm<256, 1><<<157, 256, 0, stream>>>(h_in, O1T, SB + 512, T1, NN);
  k_gemm<128, 2><<<157, 256, 0, stream>>>(T1,  O2T, SB + 640, T2, NN);

  // residual + LN
  k_ln<<<NN, 64, 0, stream>>>(NFc, T2, SB + 768, SB + 896, d_out, flag);
}